// Round 1
// baseline (763.592 us; speedup 1.0000x reference)
//
#include <hip/hip_runtime.h>

#define D 32

__global__ void deg_kernel(const int* __restrict__ row, const float* __restrict__ val,
                           float* __restrict__ deg, int E) {
    int i = blockIdx.x * blockDim.x + threadIdx.x;
    int stride = gridDim.x * blockDim.x;
    for (; i < E; i += stride)
        atomicAdd(&deg[row[i]], val[i]);
}

__global__ void dis_kernel(const float* __restrict__ deg, float* __restrict__ dis, int N) {
    int i = blockIdx.x * blockDim.x + threadIdx.x;
    if (i < N) {
        float d = deg[i];
        dis[i] = d > 0.0f ? rsqrtf(d) : 0.0f;
    }
}

// Xw[n, o] = sum_i X[n, i] * W[o, i]   (torch layout W: [out, in])
__global__ void xw_kernel(const float* __restrict__ X, const float* __restrict__ W,
                          float* __restrict__ Xw, int N) {
    __shared__ float sWt[D][D + 1];  // transposed + padded: sWt[i][o] = W[o, i]
    __shared__ float sX[8][D];
    int t = threadIdx.x;  // 256 threads
#pragma unroll
    for (int k = 0; k < 4; ++k) {
        int idx = t + k * 256;     // idx = o*32 + i
        int o = idx >> 5;
        int i = idx & 31;
        sWt[i][o] = W[idx];
    }
    int r = t >> 5, c = t & 31;
    int n = blockIdx.x * 8 + r;
    if (n < N) sX[r][c] = X[n * D + c];
    __syncthreads();
    if (n < N) {
        float acc = 0.0f;
#pragma unroll
        for (int i = 0; i < D; ++i)
            acc += sX[r][i] * sWt[i][c];   // lanes read consecutive o -> conflict-free
        Xw[n * D + c] = acc;
    }
}

// out[r, :] += dis[r]*val*dis[c] * Xw[c, :]; each thread does a float4 chunk.
__global__ void scatter_kernel(const int* __restrict__ row, const int* __restrict__ col,
                               const float* __restrict__ val, const float* __restrict__ dis,
                               const float* __restrict__ Xw, float* __restrict__ out,
                               long total) {
    long i = (long)blockIdx.x * blockDim.x + threadIdx.x;
    long stride = (long)gridDim.x * blockDim.x;
    for (; i < total; i += stride) {
        int e = (int)(i >> 3);
        int q = (int)(i & 7);
        int r = row[e];
        int c = col[e];
        float v = dis[r] * val[e] * dis[c];
        const float4 x = *reinterpret_cast<const float4*>(&Xw[c * D + q * 4]);
        float* o = &out[r * D + q * 4];
        atomicAdd(o + 0, v * x.x);
        atomicAdd(o + 1, v * x.y);
        atomicAdd(o + 2, v * x.z);
        atomicAdd(o + 3, v * x.w);
    }
}

extern "C" void kernel_launch(void* const* d_in, const int* in_sizes, int n_in,
                              void* d_out, int out_size, void* d_ws, size_t ws_size,
                              hipStream_t stream) {
    const int*   row = (const int*)d_in[0];
    const int*   col = (const int*)d_in[1];
    const float* val = (const float*)d_in[2];
    const float* X   = (const float*)d_in[3];
    const float* W   = (const float*)d_in[4];
    const int E = in_sizes[0];
    const int N = in_sizes[3] / D;

    float* out = (float*)d_out;
    float* deg = (float*)d_ws;          // N floats
    float* dis = deg + N;               // N floats
    float* Xw  = dis + N;               // N*D floats

    hipMemsetAsync(deg, 0, (size_t)N * sizeof(float), stream);
    hipMemsetAsync(out, 0, (size_t)out_size * sizeof(float), stream);

    deg_kernel<<<(E + 255) / 256, 256, 0, stream>>>(row, val, deg, E);
    dis_kernel<<<(N + 255) / 256, 256, 0, stream>>>(deg, dis, N);
    xw_kernel<<<(N + 7) / 8, 256, 0, stream>>>(X, W, Xw, N);

    const long total = (long)E * 8;  // E edges * 8 float4-chunks
    const int blocks = 8192;
    scatter_kernel<<<blocks, 256, 0, stream>>>(row, col, val, dis, Xw, out, total);
}

// Round 2
// 340.378 us; speedup vs baseline: 2.2434x; 2.2434x over previous
//
#include <hip/hip_runtime.h>

#define D 32

__global__ void deg_cnt_kernel(const int* __restrict__ row, const float* __restrict__ val,
                               float* __restrict__ deg, int* __restrict__ cnt, int E) {
    int i = blockIdx.x * blockDim.x + threadIdx.x;
    int stride = gridDim.x * blockDim.x;
    for (; i < E; i += stride) {
        int r = row[i];
        atomicAdd(&deg[r], val[i]);
        atomicAdd(&cnt[r], 1);
    }
}

__global__ void dis_kernel(const float* __restrict__ deg, float* __restrict__ dis, int N) {
    int i = blockIdx.x * blockDim.x + threadIdx.x;
    if (i < N) {
        float d = deg[i];
        dis[i] = d > 0.0f ? rsqrtf(d) : 0.0f;
    }
}

// ---- 3-kernel exclusive scan of cnt -> off ----
__global__ void scan1_kernel(const int* __restrict__ cnt, int* __restrict__ off,
                             int* __restrict__ bsum, int N) {
    __shared__ int s[256];
    int t = threadIdx.x;
    int i = blockIdx.x * 256 + t;
    int x = (i < N) ? cnt[i] : 0;
    s[t] = x;
    __syncthreads();
    for (int o = 1; o < 256; o <<= 1) {
        int v = (t >= o) ? s[t - o] : 0;
        __syncthreads();
        s[t] += v;
        __syncthreads();
    }
    if (i < N) off[i] = s[t] - x;          // exclusive within block
    if (t == 255) bsum[blockIdx.x] = s[255];
}

__global__ void scan2_kernel(int* __restrict__ bsum, int nb) {
    __shared__ int s[512];
    int t = threadIdx.x;
    int x = (t < nb) ? bsum[t] : 0;
    s[t] = x;
    __syncthreads();
    for (int o = 1; o < 512; o <<= 1) {
        int v = (t >= o) ? s[t - o] : 0;
        __syncthreads();
        s[t] += v;
        __syncthreads();
    }
    if (t < nb) bsum[t] = s[t] - x;        // exclusive
}

__global__ void scan3_kernel(int* __restrict__ off, int* __restrict__ cur,
                             const int* __restrict__ bsum, int N) {
    int i = blockIdx.x * 256 + threadIdx.x;
    if (i < N) {
        int v = off[i] + bsum[blockIdx.x];
        off[i] = v;
        cur[i] = v;
    }
}

// ---- Xw = X @ W^T ----
__global__ void xw_kernel(const float* __restrict__ X, const float* __restrict__ W,
                          float* __restrict__ Xw, int N) {
    __shared__ float sWt[D][D + 1];
    __shared__ float sX[8][D];
    int t = threadIdx.x;
#pragma unroll
    for (int k = 0; k < 4; ++k) {
        int idx = t + k * 256;
        sWt[idx & 31][idx >> 5] = W[idx];
    }
    int r = t >> 5, c = t & 31;
    int n = blockIdx.x * 8 + r;
    if (n < N) sX[r][c] = X[n * D + c];
    __syncthreads();
    if (n < N) {
        float acc = 0.0f;
#pragma unroll
        for (int i = 0; i < D; ++i)
            acc += sX[r][i] * sWt[i][c];
        Xw[n * D + c] = acc;
    }
}

// ---- fill CSR: packed[pos] = (col, dis[r]*val*dis[c]) ----
__global__ void fill_kernel(const int* __restrict__ row, const int* __restrict__ col,
                            const float* __restrict__ val, const float* __restrict__ dis,
                            int* __restrict__ cur, int2* __restrict__ packed, int E) {
    int i = blockIdx.x * blockDim.x + threadIdx.x;
    int stride = gridDim.x * blockDim.x;
    for (; i < E; i += stride) {
        int r = row[i];
        int c = col[i];
        float v = dis[r] * val[i] * dis[c];
        int pos = atomicAdd(&cur[r], 1);
        packed[pos] = make_int2(c, __float_as_int(v));
    }
}

// ---- aggregate: 32 lanes per row, out written once ----
__global__ void agg_kernel(const int* __restrict__ off, const int* __restrict__ cnt,
                           const int2* __restrict__ packed, const float* __restrict__ Xw,
                           float* __restrict__ out, int N) {
    int t = threadIdx.x;
    int r = blockIdx.x * 8 + (t >> 5);
    int d = t & 31;
    if (r >= N) return;
    int start = off[r];
    int len = cnt[r];
    float acc = 0.0f;
    for (int k = 0; k < len; ++k) {
        int2 p = packed[start + k];          // broadcast across 32 lanes
        acc += __int_as_float(p.y) * Xw[p.x * D + d];  // coalesced 128B gather
    }
    out[r * D + d] = acc;
}

extern "C" void kernel_launch(void* const* d_in, const int* in_sizes, int n_in,
                              void* d_out, int out_size, void* d_ws, size_t ws_size,
                              hipStream_t stream) {
    const int*   row = (const int*)d_in[0];
    const int*   col = (const int*)d_in[1];
    const float* val = (const float*)d_in[2];
    const float* X   = (const float*)d_in[3];
    const float* W   = (const float*)d_in[4];
    const int E = in_sizes[0];
    const int N = in_sizes[3] / D;
    float* out = (float*)d_out;

    const size_t NB = (size_t)N * sizeof(float);  // == N*sizeof(int)
    char* w = (char*)d_ws;
    float* deg    = (float*)(w);                    // N f
    int*   cnt    = (int*)  (w + NB);               // N i   (adjacent to deg for one memset)
    float* dis    = (float*)(w + 2 * NB);           // N f
    int*   off    = (int*)  (w + 3 * NB);           // N i
    int*   cur    = (int*)  (w + 4 * NB);           // N i
    int*   bsum   = (int*)  (w + 5 * NB);           // 512 i
    float* Xw     = (float*)(w + 5 * NB + 4096);    // N*D f
    int2*  packed = (int2*) (w + 5 * NB + 4096 + (size_t)N * D * sizeof(float));  // E int2

    hipMemsetAsync(deg, 0, 2 * NB, stream);  // deg + cnt

    int eb = (E + 255) / 256;
    deg_cnt_kernel<<<eb, 256, 0, stream>>>(row, val, deg, cnt, E);
    dis_kernel<<<(N + 255) / 256, 256, 0, stream>>>(deg, dis, N);

    int nb1 = (N + 255) / 256;               // 391 for N=100000 (<512)
    scan1_kernel<<<nb1, 256, 0, stream>>>(cnt, off, bsum, N);
    scan2_kernel<<<1, 512, 0, stream>>>(bsum, nb1);
    scan3_kernel<<<nb1, 256, 0, stream>>>(off, cur, bsum, N);

    xw_kernel<<<(N + 7) / 8, 256, 0, stream>>>(X, W, Xw, N);

    fill_kernel<<<eb, 256, 0, stream>>>(row, col, val, dis, cur, packed, E);
    agg_kernel<<<(N + 7) / 8, 256, 0, stream>>>(off, cnt, packed, Xw, out, N);
}